// Round 10
// baseline (392.128 us; speedup 1.0000x reference)
//
#include <hip/hip_runtime.h>

#define F 128
#define S 25
#define CH 2      // column chunks
#define CW 64     // cols per chunk (128 B bf16 rows -> 12.8 MB slice per chunk)

typedef __attribute__((ext_vector_type(8))) short bf16x8;
typedef __attribute__((ext_vector_type(4))) float f32x4;

// round-to-nearest-even f32 -> bf16 bits
__device__ __forceinline__ ushort f2bf(float f) {
    uint u = __float_as_uint(f);
    return (ushort)((u + 0x7FFFu + ((u >> 16) & 1u)) >> 16);
}
__device__ __forceinline__ float bf_lo(uint v) { return __uint_as_float(v << 16); }
__device__ __forceinline__ float bf_hi(uint v) { return __uint_as_float(v & 0xFFFF0000u); }

// neighbor_idx may arrive as int32 or int64. int64 LE with values < 2^31 has
// all odd dwords zero. Deterministic data probe.
__device__ __forceinline__ bool idx_is_i64(const int* __restrict__ p) {
    return (p[1] | p[3] | p[5] | p[7]) == 0;
}
__device__ __forceinline__ int load_idx(const int* __restrict__ p, size_t i, bool is64) {
    return is64 ? p[2 * i] : p[i];
}

// ---------------------------------------------------------------------------
// K0: pack W into MFMA B-fragment order ONCE (32 KB).
// WFg[((kt*8+nt)*64 + lane)*8 + b] = bf16(W[kt*32 + 8*(lane>>4) + b][nt*16 + (lane&15)])
// ---------------------------------------------------------------------------
__global__ __launch_bounds__(256) void pack_W(
    const float* __restrict__ W, ushort* __restrict__ WFg)
{
    const int id = blockIdx.x * 256 + threadIdx.x;   // 0..2047
    if (id >= 4 * 8 * 64) return;
    const int l  = id & 63;
    const int nt = (id >> 6) & 7;
    const int kt = id >> 9;
    const int k0 = kt * 32 + (l >> 4) * 8;
    const int nn = nt * 16 + (l & 15);
    bf16x8 fr;
    #pragma unroll
    for (int b = 0; b < 8; ++b)
        fr[b] = (short)f2bf(W[(size_t)(k0 + b) * F + nn]);
    *(bf16x8*)(WFg + (size_t)id * 8) = fr;
}

// ---------------------------------------------------------------------------
// K1: y = bf16(x) @ bf16(W) via v_mfma_f32_16x16x32_bf16 (fp32 accum).
// Epilogue: stage the block's 64x128 bf16 tile in LDS (row includes wid*16 —
// the R8 bug), then coalesced 16 B stores in K2's chunk layout.
// Layouts (learn_hip m89/m91): A row=lane&15, k=8*(lane>>4)+b;
//                              D col=lane&15, row=4*(lane>>4)+reg.
// ---------------------------------------------------------------------------
template <int CHUNKED>
__global__ __launch_bounds__(256) void gemm_xw_bf16(
    const float* __restrict__ x, const ushort* __restrict__ WFg,
    ushort* __restrict__ y, int N)
{
    __shared__ __align__(16) ushort WF[4][8][64][8];   // 32 KB
    __shared__ __align__(16) ushort Ytile[64][136];    // 17.4 KB

    const int tid  = threadIdx.x;
    const int lane = tid & 63;
    const int wid  = tid >> 6;

    // linear coalesced copy of the pre-packed fragment image (16 B/lane)
    {
        const bf16x8* src = (const bf16x8*)WFg;
        bf16x8* dst = (bf16x8*)&WF[0][0][0][0];
        #pragma unroll
        for (int i = 0; i < 8; ++i)
            dst[tid + 256 * i] = src[tid + 256 * i];
    }
    __syncthreads();

    const int n0 = blockIdx.x * 64 + wid * 16;
    const int arow = n0 + (lane & 15);
    const int arow_c = arow < N ? arow : N - 1;
    const float* xrow = x + (size_t)arow_c * F + (lane >> 4) * 8;

    f32x4 acc[8];
    #pragma unroll
    for (int nt = 0; nt < 8; ++nt) acc[nt] = (f32x4){0.f, 0.f, 0.f, 0.f};

    #pragma unroll
    for (int kt = 0; kt < 4; ++kt) {
        float4 a0 = *(const float4*)(xrow + kt * 32);
        float4 a1 = *(const float4*)(xrow + kt * 32 + 4);
        bf16x8 af;
        af[0] = (short)f2bf(a0.x); af[1] = (short)f2bf(a0.y);
        af[2] = (short)f2bf(a0.z); af[3] = (short)f2bf(a0.w);
        af[4] = (short)f2bf(a1.x); af[5] = (short)f2bf(a1.y);
        af[6] = (short)f2bf(a1.z); af[7] = (short)f2bf(a1.w);
        #pragma unroll
        for (int nt = 0; nt < 8; ++nt) {
            bf16x8 bf = *(const bf16x8*)&WF[kt][nt][lane][0];
            acc[nt] = __builtin_amdgcn_mfma_f32_16x16x32_bf16(af, bf, acc[nt], 0, 0, 0);
        }
    }

    // stage D fragments into LDS; block-local row = wid*16 + (lane>>4)*4 + r
    const int lr0  = wid * 16 + (lane >> 4) * 4;
    const int dcol = lane & 15;
    #pragma unroll
    for (int nt = 0; nt < 8; ++nt) {
        #pragma unroll
        for (int r = 0; r < 4; ++r)
            Ytile[lr0 + r][nt * 16 + dcol] = f2bf(acc[nt][r]);
    }
    __syncthreads();

    // coalesced write-out: 1024 chunks of 16 B (64 rows x 16 segs)
    const int n0b = blockIdx.x * 64;
    #pragma unroll
    for (int i = 0; i < 4; ++i) {
        const int e   = i * 256 + tid;
        const int row = e >> 4, seg = e & 15;
        const int n   = n0b + row;
        if (n < N) {
            bf16x8 val = *(const bf16x8*)&Ytile[row][seg * 8];
            if (CHUNKED) {
                const int c = seg >> 3;              // global col = seg*8 -> chunk
                const int ccol = (seg & 7) * 8;
                *(bf16x8*)&y[((size_t)c * N + n) * CW + ccol] = val;
            } else {
                *(bf16x8*)&y[(size_t)n * F + seg * 8] = val;
            }
        }
    }
}

// ---------------------------------------------------------------------------
// K2: chunked gather-average, CW=64 (128 B rows), CH=2, dwordx4 gathers.
// chunk = blockIdx & 1 rides the HW round-robin block->XCD mapping.
// Wave-instr = 8 nodes x 8 lanes (lane j covers 16 B of the 128 B row)
// -> 0.65M gather instrs (vs R9's 1.3M dwordx2). R6's occupancy collapse is
// engineered out: batches of 7/7/6/6 uint4 (<=28 data VGPRs in flight) and
// __launch_bounds__(256,8) pins the allocator at <=64 VGPR (waves/CU cliff).
// ---------------------------------------------------------------------------
__global__ __launch_bounds__(256, 8) void gather_chunked(
    const ushort* __restrict__ y, const int* __restrict__ nbr,
    const float* __restrict__ bias, float* __restrict__ out, int N)
{
    __shared__ int IDX[64 * S];

    const int tid   = threadIdx.x;
    const int chunk = blockIdx.x & (CH - 1);
    const int tile  = blockIdx.x >> 1;
    const int nbase = tile * 64;
    const long total = (long)N * S;
    const bool is64 = idx_is_i64(nbr);

    if (is64) {
        for (int e = tid; e < 64 * S; e += 256) {
            long p = (long)nbase * S + e;
            IDX[e] = (p < total) ? __builtin_nontemporal_load(&nbr[2 * p]) : 0;
        }
    } else {
        for (int e = tid; e < 64 * S; e += 256) {
            long p = (long)nbase * S + e;
            IDX[e] = (p < total) ? __builtin_nontemporal_load(&nbr[p]) : 0;
        }
    }
    __syncthreads();

    const int lane = tid & 63, wave = tid >> 6;
    const int g = lane >> 3, j = lane & 7;        // 8 nodes x 8 lanes
    const float inv = 1.0f / (float)(S + 1);
    const char* ycb = (const char*)(y + (size_t)chunk * N * CW);
    const uint joff = (uint)(j << 4);             // 16 B seg within 128 B row

    constexpr int BS[4] = {0, 7, 14, 20};
    constexpr int BC[4] = {7, 7, 6, 6};

    #pragma unroll
    for (int q = 0; q < 2; ++q) {
        const int nl = wave * 16 + q * 8 + g;     // node within tile
        const int n  = nbase + nl;
        const int nc = n < N ? n : 0;

        float a[8] = {0.f, 0.f, 0.f, 0.f, 0.f, 0.f, 0.f, 0.f};

        #pragma unroll
        for (int b = 0; b < 4; ++b) {
            uint4 v[7];
            #pragma unroll
            for (int t = 0; t < BC[b]; ++t) {
                const int s = BS[b] + t;          // s==25 -> self row
                const uint id = (s < S) ? (uint)IDX[nl * S + s] : (uint)nc;
                v[t] = *(const uint4*)(ycb + (id << 7) + joff);
            }
            #pragma unroll
            for (int t = 0; t < BC[b]; ++t) {
                a[0] += bf_lo(v[t].x); a[1] += bf_hi(v[t].x);
                a[2] += bf_lo(v[t].y); a[3] += bf_hi(v[t].y);
                a[4] += bf_lo(v[t].z); a[5] += bf_hi(v[t].z);
                a[6] += bf_lo(v[t].w); a[7] += bf_hi(v[t].w);
            }
        }

        if (n < N) {
            const float* bp = bias + chunk * CW + j * 8;
            float* op = out + (size_t)n * F + chunk * CW + j * 8;
            f32x4 o0 = {a[0] * inv + bp[0], a[1] * inv + bp[1],
                        a[2] * inv + bp[2], a[3] * inv + bp[3]};
            f32x4 o1 = {a[4] * inv + bp[4], a[5] * inv + bp[5],
                        a[6] * inv + bp[6], a[7] * inv + bp[7]};
            __builtin_nontemporal_store(o0, (f32x4*)op);
            __builtin_nontemporal_store(o1, (f32x4*)(op + 4));
        }
    }
}

// ---------------------------------------------------------------------------
// Fallback (tiny ws): fused fp32 gather+GEMM.
// ---------------------------------------------------------------------------
__global__ __launch_bounds__(256) void fused_fallback_kernel(
    const float* __restrict__ x, const int* __restrict__ nbr,
    const float* __restrict__ W, const float* __restrict__ bias,
    float* __restrict__ out, int N)
{
    __shared__ float aggs[4][F];
    const int lane = threadIdx.x & 63;
    const int wid  = threadIdx.x >> 6;
    const bool is64 = idx_is_i64(nbr);
    const float inv = 1.0f / (float)(S + 1);
    const int stride = gridDim.x * 4;

    for (int base = blockIdx.x * 4; base < N; base += stride) {
        int n = base + wid;
        bool act = n < N;
        float2 acc = make_float2(0.f, 0.f);
        if (act) {
            acc = ((const float2*)(x + (size_t)n * F))[lane];
            for (int s = 0; s < S; ++s) {
                int id = load_idx(nbr, (size_t)n * S + s, is64);
                float2 v = ((const float2*)(x + (size_t)id * F))[lane];
                acc.x += v.x; acc.y += v.y;
            }
        }
        aggs[wid][2 * lane]     = acc.x * inv;
        aggs[wid][2 * lane + 1] = acc.y * inv;
        __syncthreads();
        if (act) {
            float o0 = bias[lane], o1 = bias[lane + 64];
            for (int k = 0; k < F; ++k) {
                float a = aggs[wid][k];
                o0 += a * W[k * F + lane];
                o1 += a * W[k * F + lane + 64];
            }
            out[(size_t)n * F + lane]      = o0;
            out[(size_t)n * F + lane + 64] = o1;
        }
        __syncthreads();
    }
}

extern "C" void kernel_launch(void* const* d_in, const int* in_sizes, int n_in,
                              void* d_out, int out_size, void* d_ws, size_t ws_size,
                              hipStream_t stream) {
    const float* x    = (const float*)d_in[0];
    const int*   nbr  = (const int*)d_in[1];
    const float* W    = (const float*)d_in[2];
    const float* bias = (const float*)d_in[3];
    float* out = (float*)d_out;
    const int N = in_sizes[0] / F;                 // 100000

    const size_t y_bytes  = (size_t)N * F * sizeof(ushort);              // 25.6 MB
    const size_t wf_bytes = (size_t)4 * 8 * 64 * 8 * sizeof(ushort);     // 32 KB

    if (ws_size >= y_bytes + wf_bytes) {
        ushort* y   = (ushort*)d_ws;
        ushort* WFg = (ushort*)((char*)d_ws + y_bytes);
        pack_W<<<8, 256, 0, stream>>>(W, WFg);
        const int tiles = (N + 63) / 64;           // 1563
        gemm_xw_bf16<1><<<tiles, 256, 0, stream>>>(x, WFg, y, N);
        gather_chunked<<<tiles * CH, 256, 0, stream>>>(y, nbr, bias, out, N);
    } else {
        fused_fallback_kernel<<<2048, 256, 0, stream>>>(x, nbr, W, bias, out, N);
    }
}

// Round 11
// 104.439 us; speedup vs baseline: 3.7546x; 3.7546x over previous
//
#include <hip/hip_runtime.h>

#define F 128
#define S 25
#define CH 2      // column chunks
#define CW 64     // cols per chunk (128 B bf16 rows -> 12.8 MB slice per chunk)

typedef __attribute__((ext_vector_type(8))) short bf16x8;
typedef __attribute__((ext_vector_type(4))) float f32x4;

// round-to-nearest-even f32 -> bf16 bits
__device__ __forceinline__ ushort f2bf(float f) {
    uint u = __float_as_uint(f);
    return (ushort)((u + 0x7FFFu + ((u >> 16) & 1u)) >> 16);
}
__device__ __forceinline__ float bf_lo(uint v) { return __uint_as_float(v << 16); }
__device__ __forceinline__ float bf_hi(uint v) { return __uint_as_float(v & 0xFFFF0000u); }

// neighbor_idx may arrive as int32 or int64. int64 LE with values < 2^31 has
// all odd dwords zero. Deterministic data probe.
__device__ __forceinline__ bool idx_is_i64(const int* __restrict__ p) {
    return (p[1] | p[3] | p[5] | p[7]) == 0;
}
__device__ __forceinline__ int load_idx(const int* __restrict__ p, size_t i, bool is64) {
    return is64 ? p[2 * i] : p[i];
}

// ---------------------------------------------------------------------------
// K0: pack W into MFMA B-fragment order ONCE (32 KB).
// WFg[((kt*8+nt)*64 + lane)*8 + b] = bf16(W[kt*32 + 8*(lane>>4) + b][nt*16 + (lane&15)])
// ---------------------------------------------------------------------------
__global__ __launch_bounds__(256) void pack_W(
    const float* __restrict__ W, ushort* __restrict__ WFg)
{
    const int id = blockIdx.x * 256 + threadIdx.x;   // 0..2047
    if (id >= 4 * 8 * 64) return;
    const int l  = id & 63;
    const int nt = (id >> 6) & 7;
    const int kt = id >> 9;
    const int k0 = kt * 32 + (l >> 4) * 8;
    const int nn = nt * 16 + (l & 15);
    bf16x8 fr;
    #pragma unroll
    for (int b = 0; b < 8; ++b)
        fr[b] = (short)f2bf(W[(size_t)(k0 + b) * F + nn]);
    *(bf16x8*)(WFg + (size_t)id * 8) = fr;
}

// ---------------------------------------------------------------------------
// K1: y = bf16(x) @ bf16(W) via v_mfma_f32_16x16x32_bf16 (fp32 accum).
// Epilogue: stage the block's 64x128 bf16 tile in LDS (row includes wid*16),
// then coalesced 16 B stores in K2's chunk layout.
// Layouts (learn_hip m89/m91): A row=lane&15, k=8*(lane>>4)+b;
//                              D col=lane&15, row=4*(lane>>4)+reg.
// ---------------------------------------------------------------------------
template <int CHUNKED>
__global__ __launch_bounds__(256) void gemm_xw_bf16(
    const float* __restrict__ x, const ushort* __restrict__ WFg,
    ushort* __restrict__ y, int N)
{
    __shared__ __align__(16) ushort WF[4][8][64][8];   // 32 KB
    __shared__ __align__(16) ushort Ytile[64][136];    // 17.4 KB

    const int tid  = threadIdx.x;
    const int lane = tid & 63;
    const int wid  = tid >> 6;

    // linear coalesced copy of the pre-packed fragment image (16 B/lane)
    {
        const bf16x8* src = (const bf16x8*)WFg;
        bf16x8* dst = (bf16x8*)&WF[0][0][0][0];
        #pragma unroll
        for (int i = 0; i < 8; ++i)
            dst[tid + 256 * i] = src[tid + 256 * i];
    }
    __syncthreads();

    const int n0 = blockIdx.x * 64 + wid * 16;
    const int arow = n0 + (lane & 15);
    const int arow_c = arow < N ? arow : N - 1;
    const float* xrow = x + (size_t)arow_c * F + (lane >> 4) * 8;

    f32x4 acc[8];
    #pragma unroll
    for (int nt = 0; nt < 8; ++nt) acc[nt] = (f32x4){0.f, 0.f, 0.f, 0.f};

    #pragma unroll
    for (int kt = 0; kt < 4; ++kt) {
        float4 a0 = *(const float4*)(xrow + kt * 32);
        float4 a1 = *(const float4*)(xrow + kt * 32 + 4);
        bf16x8 af;
        af[0] = (short)f2bf(a0.x); af[1] = (short)f2bf(a0.y);
        af[2] = (short)f2bf(a0.z); af[3] = (short)f2bf(a0.w);
        af[4] = (short)f2bf(a1.x); af[5] = (short)f2bf(a1.y);
        af[6] = (short)f2bf(a1.z); af[7] = (short)f2bf(a1.w);
        #pragma unroll
        for (int nt = 0; nt < 8; ++nt) {
            bf16x8 bf = *(const bf16x8*)&WF[kt][nt][lane][0];
            acc[nt] = __builtin_amdgcn_mfma_f32_16x16x32_bf16(af, bf, acc[nt], 0, 0, 0);
        }
    }

    // stage D fragments into LDS; block-local row = wid*16 + (lane>>4)*4 + r
    const int lr0  = wid * 16 + (lane >> 4) * 4;
    const int dcol = lane & 15;
    #pragma unroll
    for (int nt = 0; nt < 8; ++nt) {
        #pragma unroll
        for (int r = 0; r < 4; ++r)
            Ytile[lr0 + r][nt * 16 + dcol] = f2bf(acc[nt][r]);
    }
    __syncthreads();

    // coalesced write-out: 1024 chunks of 16 B (64 rows x 16 segs)
    const int n0b = blockIdx.x * 64;
    #pragma unroll
    for (int i = 0; i < 4; ++i) {
        const int e   = i * 256 + tid;
        const int row = e >> 4, seg = e & 15;
        const int n   = n0b + row;
        if (n < N) {
            bf16x8 val = *(const bf16x8*)&Ytile[row][seg * 8];
            if (CHUNKED) {
                const int c = seg >> 3;              // global col = seg*8 -> chunk
                const int ccol = (seg & 7) * 8;
                *(bf16x8*)&y[((size_t)c * N + n) * CW + ccol] = val;
            } else {
                *(bf16x8*)&y[(size_t)n * F + seg * 8] = val;
            }
        }
    }
}

// ---------------------------------------------------------------------------
// K2: chunked gather-average, CW=64 (128 B rows), CH=2, dwordx4 gathers.
// chunk = blockIdx & 1 rides the HW round-robin block->XCD mapping.
// Wave-instr = 8 nodes x 8 lanes (lane j covers 16 B of the 128 B row)
// -> 0.65M gather instrs (vs R9's 1.3M dwordx2).
// R10 lesson: do NOT pin min-waves via __launch_bounds__ — forcing 8 waves/EU
// capped the allocator at 32 VGPR and spilled everything (832 MB scratch
// writes, 370 us). Instead: small batches (5/5/4/4/4/4 uint4, <=20 data regs
// in flight) and let the allocator land at ~56-64 VGPR naturally.
// ---------------------------------------------------------------------------
__global__ __launch_bounds__(256) void gather_chunked(
    const ushort* __restrict__ y, const int* __restrict__ nbr,
    const float* __restrict__ bias, float* __restrict__ out, int N)
{
    __shared__ int IDX[64 * S];

    const int tid   = threadIdx.x;
    const int chunk = blockIdx.x & (CH - 1);
    const int tile  = blockIdx.x >> 1;
    const int nbase = tile * 64;
    const long total = (long)N * S;
    const bool is64 = idx_is_i64(nbr);

    if (is64) {
        for (int e = tid; e < 64 * S; e += 256) {
            long p = (long)nbase * S + e;
            IDX[e] = (p < total) ? __builtin_nontemporal_load(&nbr[2 * p]) : 0;
        }
    } else {
        for (int e = tid; e < 64 * S; e += 256) {
            long p = (long)nbase * S + e;
            IDX[e] = (p < total) ? __builtin_nontemporal_load(&nbr[p]) : 0;
        }
    }
    __syncthreads();

    const int lane = tid & 63, wave = tid >> 6;
    const int g = lane >> 3, j = lane & 7;        // 8 nodes x 8 lanes
    const float inv = 1.0f / (float)(S + 1);
    const char* ycb = (const char*)(y + (size_t)chunk * N * CW);
    const uint joff = (uint)(j << 4);             // 16 B seg within 128 B row

    constexpr int BS[6] = {0, 5, 10, 14, 18, 22};
    constexpr int BC[6] = {5, 5, 4, 4, 4, 4};     // sums to 26 (s==25 -> self)

    #pragma unroll
    for (int q = 0; q < 2; ++q) {
        const int nl = wave * 16 + q * 8 + g;     // node within tile
        const int n  = nbase + nl;
        const int nc = n < N ? n : 0;

        float a[8] = {0.f, 0.f, 0.f, 0.f, 0.f, 0.f, 0.f, 0.f};

        #pragma unroll
        for (int b = 0; b < 6; ++b) {
            uint4 v[5];
            #pragma unroll
            for (int t = 0; t < BC[b]; ++t) {
                const int s = BS[b] + t;          // s==25 -> self row
                const uint id = (s < S) ? (uint)IDX[nl * S + s] : (uint)nc;
                v[t] = *(const uint4*)(ycb + (id << 7) + joff);
            }
            #pragma unroll
            for (int t = 0; t < BC[b]; ++t) {
                a[0] += bf_lo(v[t].x); a[1] += bf_hi(v[t].x);
                a[2] += bf_lo(v[t].y); a[3] += bf_hi(v[t].y);
                a[4] += bf_lo(v[t].z); a[5] += bf_hi(v[t].z);
                a[6] += bf_lo(v[t].w); a[7] += bf_hi(v[t].w);
            }
        }

        if (n < N) {
            const float* bp = bias + chunk * CW + j * 8;
            float* op = out + (size_t)n * F + chunk * CW + j * 8;
            f32x4 o0 = {a[0] * inv + bp[0], a[1] * inv + bp[1],
                        a[2] * inv + bp[2], a[3] * inv + bp[3]};
            f32x4 o1 = {a[4] * inv + bp[4], a[5] * inv + bp[5],
                        a[6] * inv + bp[6], a[7] * inv + bp[7]};
            __builtin_nontemporal_store(o0, (f32x4*)op);
            __builtin_nontemporal_store(o1, (f32x4*)(op + 4));
        }
    }
}

// ---------------------------------------------------------------------------
// Fallback (tiny ws): fused fp32 gather+GEMM.
// ---------------------------------------------------------------------------
__global__ __launch_bounds__(256) void fused_fallback_kernel(
    const float* __restrict__ x, const int* __restrict__ nbr,
    const float* __restrict__ W, const float* __restrict__ bias,
    float* __restrict__ out, int N)
{
    __shared__ float aggs[4][F];
    const int lane = threadIdx.x & 63;
    const int wid  = threadIdx.x >> 6;
    const bool is64 = idx_is_i64(nbr);
    const float inv = 1.0f / (float)(S + 1);
    const int stride = gridDim.x * 4;

    for (int base = blockIdx.x * 4; base < N; base += stride) {
        int n = base + wid;
        bool act = n < N;
        float2 acc = make_float2(0.f, 0.f);
        if (act) {
            acc = ((const float2*)(x + (size_t)n * F))[lane];
            for (int s = 0; s < S; ++s) {
                int id = load_idx(nbr, (size_t)n * S + s, is64);
                float2 v = ((const float2*)(x + (size_t)id * F))[lane];
                acc.x += v.x; acc.y += v.y;
            }
        }
        aggs[wid][2 * lane]     = acc.x * inv;
        aggs[wid][2 * lane + 1] = acc.y * inv;
        __syncthreads();
        if (act) {
            float o0 = bias[lane], o1 = bias[lane + 64];
            for (int k = 0; k < F; ++k) {
                float a = aggs[wid][k];
                o0 += a * W[k * F + lane];
                o1 += a * W[k * F + lane + 64];
            }
            out[(size_t)n * F + lane]      = o0;
            out[(size_t)n * F + lane + 64] = o1;
        }
        __syncthreads();
    }
}

extern "C" void kernel_launch(void* const* d_in, const int* in_sizes, int n_in,
                              void* d_out, int out_size, void* d_ws, size_t ws_size,
                              hipStream_t stream) {
    const float* x    = (const float*)d_in[0];
    const int*   nbr  = (const int*)d_in[1];
    const float* W    = (const float*)d_in[2];
    const float* bias = (const float*)d_in[3];
    float* out = (float*)d_out;
    const int N = in_sizes[0] / F;                 // 100000

    const size_t y_bytes  = (size_t)N * F * sizeof(ushort);              // 25.6 MB
    const size_t wf_bytes = (size_t)4 * 8 * 64 * 8 * sizeof(ushort);     // 32 KB

    if (ws_size >= y_bytes + wf_bytes) {
        ushort* y   = (ushort*)d_ws;
        ushort* WFg = (ushort*)((char*)d_ws + y_bytes);
        pack_W<<<8, 256, 0, stream>>>(W, WFg);
        const int tiles = (N + 63) / 64;           // 1563
        gemm_xw_bf16<1><<<tiles, 256, 0, stream>>>(x, WFg, y, N);
        gather_chunked<<<tiles * CH, 256, 0, stream>>>(y, nbr, bias, out, N);
    } else {
        fused_fallback_kernel<<<2048, 256, 0, stream>>>(x, nbr, W, bias, out, N);
    }
}

// Round 12
// 103.512 us; speedup vs baseline: 3.7883x; 1.0090x over previous
//
#include <hip/hip_runtime.h>

#define F 128
#define S 25
#define CH 2      // column chunks
#define CW 64     // cols per chunk (128 B bf16 rows -> 12.8 MB slice per chunk)

typedef __attribute__((ext_vector_type(8))) short bf16x8;
typedef __attribute__((ext_vector_type(4))) float f32x4;

// round-to-nearest-even f32 -> bf16 bits
__device__ __forceinline__ ushort f2bf(float f) {
    uint u = __float_as_uint(f);
    return (ushort)((u + 0x7FFFu + ((u >> 16) & 1u)) >> 16);
}
__device__ __forceinline__ float bf_lo(uint v) { return __uint_as_float(v << 16); }
__device__ __forceinline__ float bf_hi(uint v) { return __uint_as_float(v & 0xFFFF0000u); }

// neighbor_idx may arrive as int32 or int64. int64 LE with values < 2^31 has
// all odd dwords zero. Deterministic data probe.
__device__ __forceinline__ bool idx_is_i64(const int* __restrict__ p) {
    return (p[1] | p[3] | p[5] | p[7]) == 0;
}
__device__ __forceinline__ int load_idx(const int* __restrict__ p, size_t i, bool is64) {
    return is64 ? p[2 * i] : p[i];
}

// ---------------------------------------------------------------------------
// K0: pack W into MFMA B-fragment order ONCE (32 KB).
// WFg[((kt*8+nt)*64 + lane)*8 + b] = bf16(W[kt*32 + 8*(lane>>4) + b][nt*16 + (lane&15)])
// ---------------------------------------------------------------------------
__global__ __launch_bounds__(256) void pack_W(
    const float* __restrict__ W, ushort* __restrict__ WFg)
{
    const int id = blockIdx.x * 256 + threadIdx.x;   // 0..2047
    if (id >= 4 * 8 * 64) return;
    const int l  = id & 63;
    const int nt = (id >> 6) & 7;
    const int kt = id >> 9;
    const int k0 = kt * 32 + (l >> 4) * 8;
    const int nn = nt * 16 + (l & 15);
    bf16x8 fr;
    #pragma unroll
    for (int b = 0; b < 8; ++b)
        fr[b] = (short)f2bf(W[(size_t)(k0 + b) * F + nn]);
    *(bf16x8*)(WFg + (size_t)id * 8) = fr;
}

// ---------------------------------------------------------------------------
// K1: y = bf16(x) @ bf16(W) via v_mfma_f32_16x16x32_bf16 (fp32 accum).
// R12: 2 row-tiles (128 rows) per block -> WF copy / prologue amortized 2x,
// grid 1563 -> 782. Epilogue stages each 64x128 tile in LDS (row includes
// wid*16), then coalesced 16 B stores in K2's chunk layout.
// Layouts (learn_hip m89/m91): A row=lane&15, k=8*(lane>>4)+b;
//                              D col=lane&15, row=4*(lane>>4)+reg.
// ---------------------------------------------------------------------------
template <int CHUNKED>
__global__ __launch_bounds__(256) void gemm_xw_bf16(
    const float* __restrict__ x, const ushort* __restrict__ WFg,
    ushort* __restrict__ y, int N)
{
    __shared__ __align__(16) ushort WF[4][8][64][8];   // 32 KB
    __shared__ __align__(16) ushort Ytile[64][136];    // 17.4 KB

    const int tid  = threadIdx.x;
    const int lane = tid & 63;
    const int wid  = tid >> 6;

    // linear coalesced copy of the pre-packed fragment image (16 B/lane)
    {
        const bf16x8* src = (const bf16x8*)WFg;
        bf16x8* dst = (bf16x8*)&WF[0][0][0][0];
        #pragma unroll
        for (int i = 0; i < 8; ++i)
            dst[tid + 256 * i] = src[tid + 256 * i];
    }
    __syncthreads();

    #pragma unroll
    for (int t = 0; t < 2; ++t) {
        const int n0b = blockIdx.x * 128 + t * 64;
        const int n0  = n0b + wid * 16;
        const int arow = n0 + (lane & 15);
        const int arow_c = arow < N ? arow : N - 1;
        const float* xrow = x + (size_t)arow_c * F + (lane >> 4) * 8;

        f32x4 acc[8];
        #pragma unroll
        for (int nt = 0; nt < 8; ++nt) acc[nt] = (f32x4){0.f, 0.f, 0.f, 0.f};

        #pragma unroll
        for (int kt = 0; kt < 4; ++kt) {
            float4 a0 = *(const float4*)(xrow + kt * 32);
            float4 a1 = *(const float4*)(xrow + kt * 32 + 4);
            bf16x8 af;
            af[0] = (short)f2bf(a0.x); af[1] = (short)f2bf(a0.y);
            af[2] = (short)f2bf(a0.z); af[3] = (short)f2bf(a0.w);
            af[4] = (short)f2bf(a1.x); af[5] = (short)f2bf(a1.y);
            af[6] = (short)f2bf(a1.z); af[7] = (short)f2bf(a1.w);
            #pragma unroll
            for (int nt = 0; nt < 8; ++nt) {
                bf16x8 bf = *(const bf16x8*)&WF[kt][nt][lane][0];
                acc[nt] = __builtin_amdgcn_mfma_f32_16x16x32_bf16(af, bf, acc[nt], 0, 0, 0);
            }
        }

        // stage D fragments into LDS; block-local row = wid*16 + (lane>>4)*4 + r
        const int lr0  = wid * 16 + (lane >> 4) * 4;
        const int dcol = lane & 15;
        #pragma unroll
        for (int nt = 0; nt < 8; ++nt) {
            #pragma unroll
            for (int r = 0; r < 4; ++r)
                Ytile[lr0 + r][nt * 16 + dcol] = f2bf(acc[nt][r]);
        }
        __syncthreads();

        // coalesced write-out: 1024 chunks of 16 B (64 rows x 16 segs)
        #pragma unroll
        for (int i = 0; i < 4; ++i) {
            const int e   = i * 256 + tid;
            const int row = e >> 4, seg = e & 15;
            const int n   = n0b + row;
            if (n < N) {
                bf16x8 val = *(const bf16x8*)&Ytile[row][seg * 8];
                if (CHUNKED) {
                    const int c = seg >> 3;              // global col = seg*8 -> chunk
                    const int ccol = (seg & 7) * 8;
                    *(bf16x8*)&y[((size_t)c * N + n) * CW + ccol] = val;
                } else {
                    *(bf16x8*)&y[(size_t)n * F + seg * 8] = val;
                }
            }
        }
        __syncthreads();    // Ytile reused by next tile
    }
}

// ---------------------------------------------------------------------------
// K2: chunked gather-average, CW=64 (128 B rows), CH=2, dwordx2 gathers.
// (R9 config — best measured: 80.4 us, VGPR 36, occ 55%. R11's dwordx4 with
// half the instructions was NOT faster: the wall is 64B-segment service at
// ~5 cyc/seg/CU (~8 TB/s random), invariant across instr count & occupancy.)
// chunk = blockIdx & 1 rides the HW round-robin block->XCD mapping.
// Wave = 4 rows x 16 lanes per access (lane j covers 8 B of the 128 B row).
// idx staged in LDS directly from the raw (int64 or int32) neighbor buffer.
// ---------------------------------------------------------------------------
__global__ __launch_bounds__(256) void gather_chunked(
    const ushort* __restrict__ y, const int* __restrict__ nbr,
    const float* __restrict__ bias, float* __restrict__ out, int N)
{
    __shared__ int IDX[64 * S];

    const int tid   = threadIdx.x;
    const int chunk = blockIdx.x & (CH - 1);
    const int tile  = blockIdx.x >> 1;
    const int nbase = tile * 64;
    const long total = (long)N * S;
    const bool is64 = idx_is_i64(nbr);

    if (is64) {
        for (int e = tid; e < 64 * S; e += 256) {
            long p = (long)nbase * S + e;
            IDX[e] = (p < total) ? __builtin_nontemporal_load(&nbr[2 * p]) : 0;
        }
    } else {
        for (int e = tid; e < 64 * S; e += 256) {
            long p = (long)nbase * S + e;
            IDX[e] = (p < total) ? __builtin_nontemporal_load(&nbr[p]) : 0;
        }
    }
    __syncthreads();

    const int lane = tid & 63, wave = tid >> 6;
    const int g = lane >> 4, j = lane & 15;       // 4 rows x 16 lanes
    const float inv = 1.0f / (float)(S + 1);
    const char* ycb = (const char*)(y + (size_t)chunk * N * CW);
    const uint joff = (uint)(j << 3);             // byte offset within 128 B row
    const f32x4 bb = *(const f32x4*)(bias + chunk * CW + 4 * j);

    #pragma unroll
    for (int q = 0; q < 4; ++q) {
        const int nl = wave * 16 + q * 4 + g;     // node within tile
        const int n  = nbase + nl;
        const int nc = n < N ? n : 0;

        uint2 v[26];
        v[25] = *(const uint2*)(ycb + (((uint)nc) << 7) + joff);   // self
        #pragma unroll
        for (int s = 0; s < S; ++s) {
            const uint id = (uint)IDX[nl * S + s];
            v[s] = *(const uint2*)(ycb + (id << 7) + joff);
        }

        float a0 = 0.f, a1 = 0.f, a2 = 0.f, a3 = 0.f;
        #pragma unroll
        for (int s = 0; s < 26; ++s) {
            a0 += bf_lo(v[s].x); a1 += bf_hi(v[s].x);
            a2 += bf_lo(v[s].y); a3 += bf_hi(v[s].y);
        }

        if (n < N) {
            f32x4 o = {a0 * inv + bb.x, a1 * inv + bb.y,
                       a2 * inv + bb.z, a3 * inv + bb.w};
            __builtin_nontemporal_store(
                o, (f32x4*)(out + (size_t)n * F + chunk * CW + 4 * j));
        }
    }
}

// ---------------------------------------------------------------------------
// Fallback (tiny ws): fused fp32 gather+GEMM.
// ---------------------------------------------------------------------------
__global__ __launch_bounds__(256) void fused_fallback_kernel(
    const float* __restrict__ x, const int* __restrict__ nbr,
    const float* __restrict__ W, const float* __restrict__ bias,
    float* __restrict__ out, int N)
{
    __shared__ float aggs[4][F];
    const int lane = threadIdx.x & 63;
    const int wid  = threadIdx.x >> 6;
    const bool is64 = idx_is_i64(nbr);
    const float inv = 1.0f / (float)(S + 1);
    const int stride = gridDim.x * 4;

    for (int base = blockIdx.x * 4; base < N; base += stride) {
        int n = base + wid;
        bool act = n < N;
        float2 acc = make_float2(0.f, 0.f);
        if (act) {
            acc = ((const float2*)(x + (size_t)n * F))[lane];
            for (int s = 0; s < S; ++s) {
                int id = load_idx(nbr, (size_t)n * S + s, is64);
                float2 v = ((const float2*)(x + (size_t)id * F))[lane];
                acc.x += v.x; acc.y += v.y;
            }
        }
        aggs[wid][2 * lane]     = acc.x * inv;
        aggs[wid][2 * lane + 1] = acc.y * inv;
        __syncthreads();
        if (act) {
            float o0 = bias[lane], o1 = bias[lane + 64];
            for (int k = 0; k < F; ++k) {
                float a = aggs[wid][k];
                o0 += a * W[k * F + lane];
                o1 += a * W[k * F + lane + 64];
            }
            out[(size_t)n * F + lane]      = o0;
            out[(size_t)n * F + lane + 64] = o1;
        }
        __syncthreads();
    }
}

extern "C" void kernel_launch(void* const* d_in, const int* in_sizes, int n_in,
                              void* d_out, int out_size, void* d_ws, size_t ws_size,
                              hipStream_t stream) {
    const float* x    = (const float*)d_in[0];
    const int*   nbr  = (const int*)d_in[1];
    const float* W    = (const float*)d_in[2];
    const float* bias = (const float*)d_in[3];
    float* out = (float*)d_out;
    const int N = in_sizes[0] / F;                 // 100000

    const size_t y_bytes  = (size_t)N * F * sizeof(ushort);              // 25.6 MB
    const size_t wf_bytes = (size_t)4 * 8 * 64 * 8 * sizeof(ushort);     // 32 KB

    if (ws_size >= y_bytes + wf_bytes) {
        ushort* y   = (ushort*)d_ws;
        ushort* WFg = (ushort*)((char*)d_ws + y_bytes);
        pack_W<<<8, 256, 0, stream>>>(W, WFg);
        const int tiles64 = (N + 63) / 64;         // 1563
        const int blocks1 = (N + 127) / 128;       // 782
        gemm_xw_bf16<1><<<blocks1, 256, 0, stream>>>(x, WFg, y, N);
        gather_chunked<<<tiles64 * CH, 256, 0, stream>>>(y, nbr, bias, out, N);
    } else {
        fused_fallback_kernel<<<2048, 256, 0, stream>>>(x, nbr, W, bias, out, N);
    }
}